// Round 11
// baseline (2085.342 us; speedup 1.0000x reference)
//
#include <hip/hip_runtime.h>

// PolicyNetGCN on MI355X — round 11.
// build1 = block-aggregated counting sort (round 8). build2 decodes edges to
//   8 B {w_f32, col<<9} with zero-padded 64-slot row buckets.
// gemm1/gemm2 = MFMA 16x16x32_f16 (fp32/fp16 input -> fp16 flat).
// spmmS = XCD-SLICED gather: 8 channel-slices of 32ch (64 B/row -> 2.8 MB
//   per-XCD L2-resident). Persistent blocks read physical XCC_ID, pull
//   8-row chunks from their OWN XCD's queue (slice == queue), steal from
//   other queues when empty (correct under any dispatch placement).
//   Lane layout: 16-lane group = one row, t = channel pair; maskless
//   2-edge-per-iter loop; each gather = one 64 B line in the local L2.
//   spmm1 slice writes agg[row][slice]; spmm2 slice writes head partial
//   pout[slice][row]; comb_k sums pairs -> out.

typedef _Float16 fp16_t;
typedef _Float16 h2 __attribute__((ext_vector_type(2)));  // 4 B
typedef _Float16 h8 __attribute__((ext_vector_type(8)));  // 16 B
typedef float    f4 __attribute__((ext_vector_type(4)));
typedef unsigned long long ull;

#define CAP   64    // slots per row; P(deg>64 | ~Poisson(16)) ~ 2e-18
#define RPB   256   // rows per coarse bucket
#define BCAP  4608  // per-bucket capacity (mean 4096, sd 64 -> +8 sigma)
#define CHK   3200  // edges per phase-1 block

// build phase 1: histogram -> scan -> reserve(1 atomic/bucket) -> stage -> copy
__global__ __launch_bounds__(256) void build1_k(const int* __restrict__ erow,
                                                const int* __restrict__ ecol,
                                                const float* __restrict__ ew,
                                                int* __restrict__ gcnt,
                                                ull* __restrict__ bed,
                                                int E, int NB) {
    __shared__ int hist[256], offs[256], cur[256], gbase[256];
    __shared__ ull stage[CHK];
    __shared__ unsigned short sbkt[CHK];
    int tid = threadIdx.x;
    int e0 = blockIdx.x * CHK;
    int e1 = e0 + CHK < E ? e0 + CHK : E;

    hist[tid] = 0;
    cur[tid] = 0;
    __syncthreads();
    for (int e = e0 + tid; e < e1; e += 256)
        atomicAdd(&hist[erow[e] >> 8], 1);
    __syncthreads();
    int v = hist[tid];
    offs[tid] = v;
    __syncthreads();
    for (int off = 1; off < 256; off <<= 1) {
        int t = (tid >= off) ? offs[tid - off] : 0;
        __syncthreads();
        offs[tid] += t;
        __syncthreads();
    }
    offs[tid] -= v;  // exclusive
    if (tid < NB && v > 0) gbase[tid] = atomicAdd(&gcnt[tid], v);
    __syncthreads();
    for (int e = e0 + tid; e < e1; e += 256) {
        int r = erow[e];
        int bk = r >> 8;
        unsigned q = (unsigned)(ew[e] * 32767.f + 0.5f);  // 15-bit fixed
        ull pv = ((ull)(r & 255) << 32) | (q << 17) | (unsigned)ecol[e];
        int idx = offs[bk] + atomicAdd(&cur[bk], 1);
        stage[idx] = pv;
        sbkt[idx] = (unsigned short)bk;
    }
    __syncthreads();
    int total = e1 - e0;
    for (int i = tid; i < total; i += 256) {
        int bk = sbkt[i];
        int sl = gbase[bk] + (i - offs[bk]);
        if (sl < BCAP) bed[(size_t)bk * BCAP + sl] = stage[i];
    }
}

// build phase 2: LDS scatter, then write DECODED 8 B edges {w_f32, col<<9}.
// Zero slots decode to {0.0f, 0} -> maskless spmm reads row 0 with w=0.
__global__ __launch_bounds__(256) void build2_k(const ull* __restrict__ bed,
                                                const int* __restrict__ gcnt,
                                                ull* __restrict__ ed,
                                                int* __restrict__ cnt, int N) {
    __shared__ unsigned sbuf[RPB * CAP];  // 64 KB
    __shared__ int scnt[RPB];
    int b = blockIdx.x, tid = threadIdx.x;
    for (int i = tid; i < RPB * CAP; i += 256) sbuf[i] = 0;
    scnt[tid] = 0;
    __syncthreads();
    int n = gcnt[b];
    n = n < BCAP ? n : BCAP;
    const ull* p = bed + (size_t)b * BCAP;
    for (int i = tid; i < n; i += 256) {
        ull v = p[i];
        int rl = (int)(v >> 32);
        int pos = atomicAdd(&scnt[rl], 1);
        if (pos < CAP) sbuf[(rl << 6) + pos] = (unsigned)v;
    }
    __syncthreads();
    size_t base = (size_t)b * (RPB * CAP);
    for (int i = tid; i < RPB * CAP; i += 256) {
        unsigned pk = sbuf[i];
        float w = (float)(pk >> 17) * (1.f / 32767.f);
        ull dv = ((ull)__float_as_uint(w) << 32) | ((pk & 0x1FFFFu) << 9);
        ed[base + i] = dv;
    }
    int r = b * RPB + tid;
    if (r < N) cnt[r] = scnt[tid] < CAP ? scnt[tid] : CAP;
}

// MFMA gemm: out[n, wave*64+p] = bias[p] + sum_k x[n,wave,k] * W[k,p]
// Fragment maps (measured, m89/m91): A row=lane&15, k=8*(lane>>4)+t;
// B col=lane&15 same k; C/D col=lane&15, row=4*(lane>>4)+reg.
template <int L1>
__global__ __launch_bounds__(256) void gemmM_k(const float* __restrict__ xf,
                                               const fp16_t* __restrict__ xh,
                                               const float* __restrict__ W,
                                               const float* __restrict__ bias,
                                               fp16_t* __restrict__ out, int N) {
    int wave = threadIdx.x >> 6;       // batch 0..3
    int lane = threadIdx.x & 63;
    int r16 = lane & 15, half = lane >> 4;

    h8 Bf[2][4];
#pragma unroll
    for (int kk = 0; kk < 2; ++kk)
#pragma unroll
        for (int j = 0; j < 4; ++j) {
            h8 v;
#pragma unroll
            for (int t = 0; t < 8; ++t)
                v[t] = (_Float16)W[(32 * kk + 8 * half + t) * 64 + 16 * j + r16];
            Bf[kk][j] = v;
        }
    float bj[4];
#pragma unroll
    for (int j = 0; j < 4; ++j) bj[j] = bias[16 * j + r16];

    int ntile = N >> 4;
    for (int tile = blockIdx.x; tile < ntile; tile += gridDim.x) {
        int row = tile * 16 + r16;
        h8 A0, A1;
        if (L1) {
            const float* p = xf + ((size_t)wave * N + row) * 64 + 8 * half;
            f4 u0 = *(const f4*)p;
            f4 u1 = *(const f4*)(p + 4);
            f4 u2 = *(const f4*)(p + 32);
            f4 u3 = *(const f4*)(p + 36);
#pragma unroll
            for (int t = 0; t < 4; ++t) {
                A0[t] = (_Float16)u0[t]; A0[t + 4] = (_Float16)u1[t];
                A1[t] = (_Float16)u2[t]; A1[t + 4] = (_Float16)u3[t];
            }
        } else {
            const fp16_t* p = xh + (size_t)row * 256 + wave * 64 + 8 * half;
            A0 = *(const h8*)p;
            A1 = *(const h8*)(p + 32);
        }
#pragma unroll
        for (int j = 0; j < 4; ++j) {
            f4 c = {0.f, 0.f, 0.f, 0.f};
            c = __builtin_amdgcn_mfma_f32_16x16x32_f16(A0, Bf[0][j], c, 0, 0, 0);
            c = __builtin_amdgcn_mfma_f32_16x16x32_f16(A1, Bf[1][j], c, 0, 0, 0);
#pragma unroll
            for (int r = 0; r < 4; ++r) {
                int orow = tile * 16 + 4 * half + r;
                out[(size_t)orow * 256 + wave * 64 + 16 * j + r16] =
                    (fp16_t)(c[r] + bj[j]);
            }
        }
    }
}

// XCD-sliced SpMM. HEAD=0: write agg slice; HEAD=1: write head partials.
template <int HEAD>
__global__ __launch_bounds__(256) void spmmS_k(const fp16_t* __restrict__ flat,
                                               const int* __restrict__ cnt,
                                               const ull* __restrict__ ed,
                                               int* __restrict__ q,
                                               fp16_t* __restrict__ agg,
                                               const float* __restrict__ wout,
                                               float* __restrict__ pout, int N) {
    unsigned myx;
    asm volatile("s_getreg_b32 %0, hwreg(HW_REG_XCC_ID)" : "=s"(myx));
    myx &= 7;
    int lane = threadIdx.x & 63;
    int g = lane >> 4, t = lane & 15;
    const char* fb = (const char*)flat;
    int qi = myx;
    for (;;) {
        int r0;
        if (lane == 0) r0 = atomicAdd(&q[qi], 8);
        r0 = __shfl(r0, 0);
        if (r0 >= N) {  // this queue drained: steal from next (correct under
            qi = (qi + 1) & 7;  // any block->XCD placement; slice == queue)
            if (qi == (int)myx) break;
            continue;
        }
        int soff = qi * 64 + t * 4;  // byte offset of this slice's lane pair
        float2 wo;
        if (HEAD) wo = ((const float2*)wout)[(qi & 1) * 16 + t];
#pragma unroll
        for (int quad = 0; quad < 2; ++quad) {
            int row = r0 + quad * 4 + g;        // 16-lane group owns one row
            int mm = cnt[row];
            mm = max(mm, __shfl_xor(mm, 16));   // shared trip = max of 4 rows
            mm = max(mm, __shfl_xor(mm, 32));
            int mr = (mm + 1) & ~1;
            const ull* ep = ed + (size_t)row * CAP;
            float a0 = 0.f, a1 = 0.f;
            for (int j = 0; j < mr; j += 2) {   // maskless; pads are {0,0}
                ull m0 = ep[j];
                ull m1 = ep[j + 1];
                float w0 = __uint_as_float((unsigned)(m0 >> 32));
                float w1 = __uint_as_float((unsigned)(m1 >> 32));
                h2 v0 = *(const h2*)(fb + (unsigned)m0 + soff);  // 1 line/edge
                h2 v1 = *(const h2*)(fb + (unsigned)m1 + soff);
                a0 += w0 * (float)v0.x; a1 += w0 * (float)v0.y;
                a0 += w1 * (float)v1.x; a1 += w1 * (float)v1.y;
            }
            if (HEAD) {
                float p = fmaxf(a0, 0.f) * wo.x + fmaxf(a1, 0.f) * wo.y;
                p += __shfl_xor(p, 1); p += __shfl_xor(p, 2);
                p += __shfl_xor(p, 4); p += __shfl_xor(p, 8);
                if (t == 0) pout[(size_t)qi * N + row] = p;
            } else {
                h2 r;
                r.x = (fp16_t)fmaxf(a0, 0.f);
                r.y = (fp16_t)fmaxf(a1, 0.f);
                *(h2*)&agg[(size_t)row * 256 + qi * 32 + 2 * t] = r;
            }
        }
    }
}

// out[b][row] = pout[2b][row] + pout[2b+1][row]
__global__ __launch_bounds__(256) void comb_k(const float* __restrict__ pout,
                                              float* __restrict__ out, int N) {
    int i = blockIdx.x * 256 + threadIdx.x;
    if (i >= N) return;
#pragma unroll
    for (int b = 0; b < 4; ++b)
        out[(size_t)b * N + i] =
            pout[(size_t)(2 * b) * N + i] + pout[(size_t)(2 * b + 1) * N + i];
}

extern "C" void kernel_launch(void* const* d_in, const int* in_sizes, int n_in,
                              void* d_out, int out_size, void* d_ws, size_t ws_size,
                              hipStream_t stream) {
    const float* state = (const float*)d_in[0];
    const int*   erow  = (const int*)d_in[1];
    const int*   ecol  = (const int*)d_in[2];
    const float* ew    = (const float*)d_in[3];
    const float* W1    = (const float*)d_in[4];
    const float* b1    = (const float*)d_in[5];
    const float* W2    = (const float*)d_in[6];
    const float* b2    = (const float*)d_in[7];
    const float* wout  = (const float*)d_in[8];
    float* out = (float*)d_out;

    int N = in_sizes[0] / (4 * 64);  // 50000
    int E = in_sizes[1];             // 800000
    int NB = (N + RPB - 1) / RPB;    // 196 coarse buckets

    char* ws = (char*)d_ws;
    size_t off = 0;
    auto alloc = [&](size_t bytes) -> char* {
        char* p = ws + off;
        off += (bytes + 255) & ~(size_t)255;
        return p;
    };
    fp16_t* flat1 = (fp16_t*)alloc((size_t)N * 256 * 2);           // 25.6 MB
    fp16_t* flat2 = (fp16_t*)alloc((size_t)N * 256 * 2);           // 25.6 MB
    fp16_t* agg   = (fp16_t*)alloc((size_t)N * 256 * 2);           // 25.6 MB
    int*    cnt   = (int*)alloc((size_t)NB * RPB * 4);             // 200 KB
    ull*    ed    = (ull*)alloc((size_t)NB * RPB * CAP * 8);       // 25.7 MB
    ull*    bed   = (ull*)alloc((size_t)NB * BCAP * 8);            // 7.2 MB
    float*  pout  = (float*)alloc((size_t)8 * N * 4);              // 1.6 MB
    int*    aux   = (int*)alloc((size_t)(NB + 16) * 4);            // gcnt|q1|q2
    if (off > ws_size) return;
    int* gcnt = aux;
    int* q1   = aux + NB;
    int* q2   = aux + NB + 8;

    // --- edge build ---
    hipMemsetAsync(aux, 0, (size_t)(NB + 16) * 4, stream);
    int nblk1 = (E + CHK - 1) / CHK;  // 250
    build1_k<<<nblk1, 256, 0, stream>>>(erow, ecol, ew, gcnt, bed, E, NB);
    build2_k<<<NB, 256, 0, stream>>>(bed, gcnt, ed, cnt, N);

    // --- layer 1 ---
    gemmM_k<1><<<1024, 256, 0, stream>>>(state, (const fp16_t*)nullptr, W1, b1, flat1, N);
    spmmS_k<0><<<2048, 256, 0, stream>>>(flat1, cnt, ed, q1, agg, nullptr, nullptr, N);
    // --- layer 2 ---
    gemmM_k<0><<<1024, 256, 0, stream>>>(nullptr, agg, W2, b2, flat2, N);
    spmmS_k<1><<<2048, 256, 0, stream>>>(flat2, cnt, ed, q2, nullptr, wout, pout, N);
    // --- head combine ---
    comb_k<<<(N + 255) / 256, 256, 0, stream>>>(pout, out, N);
}

// Round 12
// 169.112 us; speedup vs baseline: 12.3311x; 12.3311x over previous
//
#include <hip/hip_runtime.h>

// PolicyNetGCN on MI355X — round 12 (revert to r10 + quad-interleave spmmG).
// build = block-aggregated 2-pass counting sort (4 B packed edges, zero-pad).
// prepW = pack W2/b2 fragments + zero gcnt (one dispatch saved).
// gemm1 = MFMA (fp32 state -> fp16 flat1), grid-stride.
// spmmG = spmm1+gemm2 fused; each wave gathers its 4 rows QUAD-interleaved
//         (16 gathers / 8 KB in flight), LDS-staged agg, 8 MFMAs -> flat2.
// spmm2h = single-pass gather + fused actor head.
// XCD channel-slicing is permanently dead: 8x edge-meta duplication + MLP
// collapse (r2, r11). Full-width 512 B row gathers are the right structure.

typedef _Float16 fp16_t;
typedef _Float16 h4 __attribute__((ext_vector_type(4)));  // 8 B
typedef _Float16 h8 __attribute__((ext_vector_type(8)));  // 16 B
typedef float    f4 __attribute__((ext_vector_type(4)));
typedef unsigned long long ull;

#define CAP   64    // slots per row; P(deg>64 | ~Poisson(16)) ~ 2e-18
#define RPB   256   // rows per coarse bucket
#define BCAP  4608  // per-bucket capacity (mean 4096, sd 64 -> +8 sigma)
#define CHK   3200  // edges per phase-1 block
#define LROW  264   // LDS agg row stride in fp16 (256 + 8 pad)

// build phase 1: histogram -> scan -> reserve(1 atomic/bucket) -> stage -> copy
__global__ __launch_bounds__(256) void build1_k(const int* __restrict__ erow,
                                                const int* __restrict__ ecol,
                                                const float* __restrict__ ew,
                                                int* __restrict__ gcnt,
                                                ull* __restrict__ bed,
                                                int E, int NB) {
    __shared__ int hist[256], offs[256], cur[256], gbase[256];
    __shared__ ull stage[CHK];
    __shared__ unsigned short sbkt[CHK];
    int tid = threadIdx.x;
    int e0 = blockIdx.x * CHK;
    int e1 = e0 + CHK < E ? e0 + CHK : E;

    hist[tid] = 0;
    cur[tid] = 0;
    __syncthreads();
    for (int e = e0 + tid; e < e1; e += 256)
        atomicAdd(&hist[erow[e] >> 8], 1);
    __syncthreads();
    int v = hist[tid];
    offs[tid] = v;
    __syncthreads();
    for (int off = 1; off < 256; off <<= 1) {
        int t = (tid >= off) ? offs[tid - off] : 0;
        __syncthreads();
        offs[tid] += t;
        __syncthreads();
    }
    offs[tid] -= v;  // exclusive
    if (tid < NB && v > 0) gbase[tid] = atomicAdd(&gcnt[tid], v);
    __syncthreads();
    for (int e = e0 + tid; e < e1; e += 256) {
        int r = erow[e];
        int bk = r >> 8;
        unsigned q = (unsigned)(ew[e] * 32767.f + 0.5f);  // 15-bit fixed
        ull pv = ((ull)(r & 255) << 32) | (q << 17) | (unsigned)ecol[e];
        int idx = offs[bk] + atomicAdd(&cur[bk], 1);
        stage[idx] = pv;
        sbkt[idx] = (unsigned short)bk;
    }
    __syncthreads();
    int total = e1 - e0;
    for (int i = tid; i < total; i += 256) {
        int bk = sbkt[i];
        int sl = gbase[bk] + (i - offs[bk]);
        if (sl < BCAP) bed[(size_t)bk * BCAP + sl] = stage[i];
    }
}

// build phase 2: LDS-staged fine scatter, fully coalesced global writes
__global__ __launch_bounds__(256) void build2_k(const ull* __restrict__ bed,
                                                const int* __restrict__ gcnt,
                                                unsigned* __restrict__ ed,
                                                int* __restrict__ cnt, int N) {
    __shared__ unsigned sbuf[RPB * CAP];  // 64 KB
    __shared__ int scnt[RPB];
    int b = blockIdx.x, tid = threadIdx.x;
    for (int i = tid; i < RPB * CAP; i += 256) sbuf[i] = 0;
    scnt[tid] = 0;
    __syncthreads();
    int n = gcnt[b];
    n = n < BCAP ? n : BCAP;
    const ull* p = bed + (size_t)b * BCAP;
    for (int i = tid; i < n; i += 256) {
        ull v = p[i];
        int rl = (int)(v >> 32);
        int pos = atomicAdd(&scnt[rl], 1);
        if (pos < CAP) sbuf[(rl << 6) + pos] = (unsigned)v;
    }
    __syncthreads();
    size_t base = (size_t)b * (RPB * CAP);
    for (int i = tid; i < RPB * CAP; i += 256)
        ed[base + i] = sbuf[i];
    int r = b * RPB + tid;
    if (r < N) cnt[r] = scnt[tid] < CAP ? scnt[tid] : CAP;
}

// pack W2/b2 into fragment order + zero gcnt
__global__ __launch_bounds__(64) void prepW_k(const float* __restrict__ W,
                                              const float* __restrict__ bias,
                                              fp16_t* __restrict__ wf,
                                              float* __restrict__ bf,
                                              int* __restrict__ gcnt, int NB) {
    int lane = threadIdx.x;
    for (int i = lane; i < NB; i += 64) gcnt[i] = 0;
    int r16 = lane & 15, half = lane >> 4;
#pragma unroll
    for (int kk = 0; kk < 2; ++kk)
#pragma unroll
        for (int j = 0; j < 4; ++j) {
            h8 v;
#pragma unroll
            for (int t = 0; t < 8; ++t)
                v[t] = (_Float16)W[(32 * kk + 8 * half + t) * 64 + 16 * j + r16];
            *(h8*)&wf[((kk * 4 + j) * 64 + lane) * 8] = v;
        }
#pragma unroll
    for (int j = 0; j < 4; ++j) bf[j * 64 + lane] = bias[16 * j + r16];
}

// MFMA gemm1: flat1[n, wave*64+p] = b1[p] + sum_k state[wave,n,k] * W1[k,p]
// Fragment maps (measured, m89/m91): A row=lane&15, k=8*(lane>>4)+t;
// B col=lane&15 same k; C/D col=lane&15, row=4*(lane>>4)+reg.
__global__ __launch_bounds__(256) void gemm1_k(const float* __restrict__ xf,
                                               const float* __restrict__ W,
                                               const float* __restrict__ bias,
                                               fp16_t* __restrict__ out, int N) {
    int wave = threadIdx.x >> 6;       // batch 0..3
    int lane = threadIdx.x & 63;
    int r16 = lane & 15, half = lane >> 4;

    h8 Bf[2][4];
#pragma unroll
    for (int kk = 0; kk < 2; ++kk)
#pragma unroll
        for (int j = 0; j < 4; ++j) {
            h8 v;
#pragma unroll
            for (int t = 0; t < 8; ++t)
                v[t] = (_Float16)W[(32 * kk + 8 * half + t) * 64 + 16 * j + r16];
            Bf[kk][j] = v;
        }
    float bj[4];
#pragma unroll
    for (int j = 0; j < 4; ++j) bj[j] = bias[16 * j + r16];

    int ntile = N >> 4;
    for (int tile = blockIdx.x; tile < ntile; tile += gridDim.x) {
        int row = tile * 16 + r16;
        const float* p = xf + ((size_t)wave * N + row) * 64 + 8 * half;
        f4 u0 = *(const f4*)p;
        f4 u1 = *(const f4*)(p + 4);
        f4 u2 = *(const f4*)(p + 32);
        f4 u3 = *(const f4*)(p + 36);
        h8 A0, A1;
#pragma unroll
        for (int t = 0; t < 4; ++t) {
            A0[t] = (_Float16)u0[t]; A0[t + 4] = (_Float16)u1[t];
            A1[t] = (_Float16)u2[t]; A1[t + 4] = (_Float16)u3[t];
        }
#pragma unroll
        for (int j = 0; j < 4; ++j) {
            f4 c = {0.f, 0.f, 0.f, 0.f};
            c = __builtin_amdgcn_mfma_f32_16x16x32_f16(A0, Bf[0][j], c, 0, 0, 0);
            c = __builtin_amdgcn_mfma_f32_16x16x32_f16(A1, Bf[1][j], c, 0, 0, 0);
#pragma unroll
            for (int r = 0; r < 4; ++r) {
                int orow = tile * 16 + 4 * half + r;
                out[(size_t)orow * 256 + wave * 64 + 16 * j + r16] =
                    (fp16_t)(c[r] + bj[j]);
            }
        }
    }
}

// One edge: decode (col17|w15), gather 8 B (h4) of the 512 B row into the
// named accumulators. Zero slots: col=0, w=0 (harmless L2-hot read).
#define EDGE4(pk, A0, A1, A2, A3)                                              \
    {                                                                          \
        unsigned _p = (pk);                                                    \
        float _w = (float)(_p >> 17) * (1.f / 32767.f);                        \
        h4 _v = base[(size_t)(_p & 0x1FFFFu) * 64];                            \
        A0 += _w * (float)_v.x; A1 += _w * (float)_v.y;                        \
        A2 += _w * (float)_v.z; A3 += _w * (float)_v.w;                        \
    }

// spmm1 + gemm2 fused. Block = 16 rows, 4 waves; wave w gathers its 4 rows
// QUAD-interleaved (16 independent 512 B gathers in flight), relu -> LDS,
// then computes batch-w's 16x64 support2 tile with 8 MFMAs -> flat2.
__global__ __launch_bounds__(256) void spmmG_k(const fp16_t* __restrict__ flat,
                                               const int* __restrict__ cnt,
                                               const unsigned* __restrict__ ed,
                                               const fp16_t* __restrict__ wf,
                                               const float* __restrict__ bf,
                                               fp16_t* __restrict__ flat2, int N) {
    __shared__ fp16_t sagg[16 * LROW];  // 8.4 KB
    int wave = threadIdx.x >> 6;   // local row group / batch index
    int lane = threadIdx.x & 63;
    int r16 = lane & 15, half = lane >> 4;

    // fragment-ordered W2/b2: 8 coalesced 16 B loads + 4 scalar loads
    h8 Bf[8];
#pragma unroll
    for (int i = 0; i < 8; ++i) Bf[i] = ((const h8*)wf)[i * 64 + lane];
    float bj[4];
#pragma unroll
    for (int j = 0; j < 4; ++j) bj[j] = bf[j * 64 + lane];

    int blk0 = blockIdx.x * 16;
    const h4* base = (const h4*)flat + lane;

    int lr = wave * 4;
    int r0 = blk0 + lr;
    int m0 = __builtin_amdgcn_readfirstlane(cnt[r0]);
    int m1 = __builtin_amdgcn_readfirstlane(cnt[r0 + 1]);
    int m2 = __builtin_amdgcn_readfirstlane(cnt[r0 + 2]);
    int m3 = __builtin_amdgcn_readfirstlane(cnt[r0 + 3]);
    int mm = max(max(m0, m1), max(m2, m3));
    int mr = (mm + 3) & ~3;
    const unsigned* e0 = ed + (size_t)r0 * CAP;
    const unsigned* e1 = e0 + CAP;
    const unsigned* e2 = e1 + CAP;
    const unsigned* e3 = e2 + CAP;
    float a00 = 0.f, a01 = 0.f, a02 = 0.f, a03 = 0.f;
    float a10 = 0.f, a11 = 0.f, a12 = 0.f, a13 = 0.f;
    float a20 = 0.f, a21 = 0.f, a22 = 0.f, a23 = 0.f;
    float a30 = 0.f, a31 = 0.f, a32 = 0.f, a33 = 0.f;
    for (int j = 0; j < mr; j += 4) {  // 16 gathers in flight (4 rows x 4)
        uint4 p0 = *(const uint4*)(e0 + j);
        uint4 p1 = *(const uint4*)(e1 + j);
        uint4 p2 = *(const uint4*)(e2 + j);
        uint4 p3 = *(const uint4*)(e3 + j);
        EDGE4(p0.x, a00, a01, a02, a03) EDGE4(p1.x, a10, a11, a12, a13)
        EDGE4(p2.x, a20, a21, a22, a23) EDGE4(p3.x, a30, a31, a32, a33)
        EDGE4(p0.y, a00, a01, a02, a03) EDGE4(p1.y, a10, a11, a12, a13)
        EDGE4(p2.y, a20, a21, a22, a23) EDGE4(p3.y, a30, a31, a32, a33)
        EDGE4(p0.z, a00, a01, a02, a03) EDGE4(p1.z, a10, a11, a12, a13)
        EDGE4(p2.z, a20, a21, a22, a23) EDGE4(p3.z, a30, a31, a32, a33)
        EDGE4(p0.w, a00, a01, a02, a03) EDGE4(p1.w, a10, a11, a12, a13)
        EDGE4(p2.w, a20, a21, a22, a23) EDGE4(p3.w, a30, a31, a32, a33)
    }
    h4 s;
    s.x = (fp16_t)fmaxf(a00, 0.f); s.y = (fp16_t)fmaxf(a01, 0.f);
    s.z = (fp16_t)fmaxf(a02, 0.f); s.w = (fp16_t)fmaxf(a03, 0.f);
    *(h4*)&sagg[(lr + 0) * LROW + lane * 4] = s;
    s.x = (fp16_t)fmaxf(a10, 0.f); s.y = (fp16_t)fmaxf(a11, 0.f);
    s.z = (fp16_t)fmaxf(a12, 0.f); s.w = (fp16_t)fmaxf(a13, 0.f);
    *(h4*)&sagg[(lr + 1) * LROW + lane * 4] = s;
    s.x = (fp16_t)fmaxf(a20, 0.f); s.y = (fp16_t)fmaxf(a21, 0.f);
    s.z = (fp16_t)fmaxf(a22, 0.f); s.w = (fp16_t)fmaxf(a23, 0.f);
    *(h4*)&sagg[(lr + 2) * LROW + lane * 4] = s;
    s.x = (fp16_t)fmaxf(a30, 0.f); s.y = (fp16_t)fmaxf(a31, 0.f);
    s.z = (fp16_t)fmaxf(a32, 0.f); s.w = (fp16_t)fmaxf(a33, 0.f);
    *(h4*)&sagg[(lr + 3) * LROW + lane * 4] = s;
    __syncthreads();

    // gemm2: wave = batch. A: row=lane&15 (local), k=8*half+t from LDS.
    h8 A0 = *(const h8*)&sagg[r16 * LROW + wave * 64 + 8 * half];
    h8 A1 = *(const h8*)&sagg[r16 * LROW + wave * 64 + 32 + 8 * half];
#pragma unroll
    for (int j = 0; j < 4; ++j) {
        f4 c = {0.f, 0.f, 0.f, 0.f};
        c = __builtin_amdgcn_mfma_f32_16x16x32_f16(A0, Bf[j], c, 0, 0, 0);
        c = __builtin_amdgcn_mfma_f32_16x16x32_f16(A1, Bf[4 + j], c, 0, 0, 0);
#pragma unroll
        for (int r = 0; r < 4; ++r) {
            int orow = blk0 + 4 * half + r;
            flat2[(size_t)orow * 256 + wave * 64 + 16 * j + r16] =
                (fp16_t)(c[r] + bj[j]);
        }
    }
}

// spmm2 + actor head: out[b, rowi] = sum_d relu(agg2[b,d]) * wout[d].
// Lane owns ch 4*lane..4*lane+3 -> b = lane>>4, d = 4*(lane&15)+i.
__global__ __launch_bounds__(256) void spmm2h_k(const fp16_t* __restrict__ flat,
                                                const int* __restrict__ cnt,
                                                const unsigned* __restrict__ ed,
                                                const float* __restrict__ wout,
                                                float* __restrict__ out, int N) {
    int rowi = blockIdx.x * 4 + (int)(threadIdx.x >> 6);
    int lane = threadIdx.x & 63;
    const h4* base = (const h4*)flat + lane;
    int m = __builtin_amdgcn_readfirstlane(cnt[rowi]);
    int mr = (m + 7) & ~7;
    const unsigned* ep = ed + (size_t)rowi * CAP;
    float a0 = 0.f, a1 = 0.f, a2 = 0.f, a3 = 0.f;
    for (int j = 0; j < mr; j += 8) {
        uint4 pA = *(const uint4*)(ep + j);
        uint4 pB = *(const uint4*)(ep + j + 4);
        EDGE4(pA.x, a0, a1, a2, a3) EDGE4(pA.y, a0, a1, a2, a3)
        EDGE4(pA.z, a0, a1, a2, a3) EDGE4(pA.w, a0, a1, a2, a3)
        EDGE4(pB.x, a0, a1, a2, a3) EDGE4(pB.y, a0, a1, a2, a3)
        EDGE4(pB.z, a0, a1, a2, a3) EDGE4(pB.w, a0, a1, a2, a3)
    }
    int t = lane & 15, b = lane >> 4;
    float4 wo = ((const float4*)wout)[t];
    float p = fmaxf(a0, 0.f) * wo.x + fmaxf(a1, 0.f) * wo.y +
              fmaxf(a2, 0.f) * wo.z + fmaxf(a3, 0.f) * wo.w;
    p += __shfl_xor(p, 1); p += __shfl_xor(p, 2);
    p += __shfl_xor(p, 4); p += __shfl_xor(p, 8);
    if (t == 0) out[(size_t)b * N + rowi] = p;
}

extern "C" void kernel_launch(void* const* d_in, const int* in_sizes, int n_in,
                              void* d_out, int out_size, void* d_ws, size_t ws_size,
                              hipStream_t stream) {
    const float* state = (const float*)d_in[0];
    const int*   erow  = (const int*)d_in[1];
    const int*   ecol  = (const int*)d_in[2];
    const float* ew    = (const float*)d_in[3];
    const float* W1    = (const float*)d_in[4];
    const float* b1    = (const float*)d_in[5];
    const float* W2    = (const float*)d_in[6];
    const float* b2    = (const float*)d_in[7];
    const float* wout  = (const float*)d_in[8];
    float* out = (float*)d_out;

    int N = in_sizes[0] / (4 * 64);  // 50000
    int E = in_sizes[1];             // 800000
    int NB = (N + RPB - 1) / RPB;    // 196 coarse buckets

    char* ws = (char*)d_ws;
    size_t off = 0;
    auto alloc = [&](size_t bytes) -> char* {
        char* p = ws + off;
        off += (bytes + 255) & ~(size_t)255;
        return p;
    };
    fp16_t*   flat1 = (fp16_t*)alloc((size_t)N * 256 * 2);           // 25.6 MB
    fp16_t*   flat2 = (fp16_t*)alloc((size_t)N * 256 * 2);           // 25.6 MB
    int*      cnt   = (int*)alloc((size_t)NB * RPB * 4);             // 200 KB
    unsigned* ed    = (unsigned*)alloc((size_t)NB * RPB * CAP * 4);  // 12.85 MB
    int*      gcnt  = (int*)alloc((size_t)NB * 4);                   // 784 B
    ull*      bed   = (ull*)alloc((size_t)NB * BCAP * 8);            // 7.2 MB
    fp16_t*   wf    = (fp16_t*)alloc(8 * 64 * 8 * 2);                // 8 KB
    float*    bfr   = (float*)alloc(4 * 64 * 4);                     // 1 KB
    if (off > ws_size) return;

    // --- prep (W2 fragments + gcnt zero) + edge build ---
    prepW_k<<<1, 64, 0, stream>>>(W2, b2, wf, bfr, gcnt, NB);
    int nblk1 = (E + CHK - 1) / CHK;  // 250
    build1_k<<<nblk1, 256, 0, stream>>>(erow, ecol, ew, gcnt, bed, E, NB);
    build2_k<<<NB, 256, 0, stream>>>(bed, gcnt, ed, cnt, N);

    // --- layer 1 gemm ---
    gemm1_k<<<1024, 256, 0, stream>>>(state, W1, b1, flat1, N);
    // --- layer 1 spmm + layer 2 gemm (fused) ---
    spmmG_k<<<N / 16, 256, 0, stream>>>(flat1, cnt, ed, wf, bfr, flat2, N);
    // --- layer 2 spmm + head (fused) ---
    spmm2h_k<<<(N + 3) / 4, 256, 0, stream>>>(flat2, cnt, ed, wout, out, N);
}